// Round 3
// baseline (4821.843 us; speedup 1.0000x reference)
//
#include <hip/hip_runtime.h>
#include <math.h>

#define N_NODES 100000
#define DIM 64
#define E_EDGES 1600000
#define N_ADJ 4
#define NB 1563            // ceil(100000/64) row-group buckets
#define CAP 1280           // bucket capacity; mean load 1024, +8 sigma

// ---------------- GEMM: s0 = x @ W + b ----------------
__global__ __launch_bounds__(256) void gemm_kernel(
    const float* __restrict__ x, const float* __restrict__ W,
    const float* __restrict__ b, float* __restrict__ h) {
    __shared__ float Ws[DIM * DIM];
    __shared__ float xs[16 * DIM];
    const int tid = threadIdx.x;
    const long row0 = (long)blockIdx.x * 16;
    for (int i = tid; i < DIM * DIM; i += 256) Ws[i] = W[i];
    for (int i = tid; i < 16 * DIM; i += 256) xs[i] = x[row0 * DIM + i];
    __syncthreads();
    const int lane = tid & 63;
    const int grp  = tid >> 6;
    const float bias = b[lane];
    #pragma unroll
    for (int rr = 0; rr < 4; ++rr) {
        const int r = grp * 4 + rr;
        float acc = bias;
        #pragma unroll
        for (int k = 0; k < DIM; ++k)
            acc += xs[r * DIM + k] * Ws[k * DIM + lane];
        h[(row0 + r) * DIM + lane] = acc;
    }
}

// ---------------- Binning: edges -> row-group buckets ----------------
// packed = (col << 6) | (row & 63); bucket = row >> 6.
__global__ __launch_bounds__(256) void bin_kernel(
    const int* __restrict__ rows, const int* __restrict__ cols,
    const float* __restrict__ vals, int* __restrict__ cnt,
    int2* __restrict__ bins) {
    const int a = blockIdx.y;
    const long i = (long)a * E_EDGES + (long)blockIdx.x * 256 + threadIdx.x;
    const int   r = rows[i];
    const int   c = cols[i];
    const float v = vals[i];
    const int bucket = a * NB + (r >> 6);
    const int slot = atomicAdd(&cnt[bucket], 1);
    if (slot < CAP)
        bins[(long)bucket * CAP + slot] =
            make_int2((c << 6) | (r & 63), __float_as_int(v));
}

// ---------------- Bucket-segment accumulate into LDS ----------------
__device__ __forceinline__ void accum_seg(
    const float* __restrict__ src, const int2* __restrict__ bins,
    const int* __restrict__ cnt, int bucket, float* acc,
    int wave, int lane) {
    const int n = min(cnt[bucket], CAP);
    const int2* seg = bins + (long)bucket * CAP;
    for (int j0 = wave * 64; j0 < n; j0 += 256) {
        const int m = min(64, n - j0);
        int2 e = make_int2(0, 0);
        if (lane < m) e = seg[j0 + lane];
        int j = 0;
        for (; j + 4 <= m; j += 4) {
            const int p0 = __shfl(e.x, j + 0);
            const int p1 = __shfl(e.x, j + 1);
            const int p2 = __shfl(e.x, j + 2);
            const int p3 = __shfl(e.x, j + 3);
            const float v0 = __int_as_float(__shfl(e.y, j + 0));
            const float v1 = __int_as_float(__shfl(e.y, j + 1));
            const float v2 = __int_as_float(__shfl(e.y, j + 2));
            const float v3 = __int_as_float(__shfl(e.y, j + 3));
            const float x0 = src[(long)(p0 >> 6) * DIM + lane];
            const float x1 = src[(long)(p1 >> 6) * DIM + lane];
            const float x2 = src[(long)(p2 >> 6) * DIM + lane];
            const float x3 = src[(long)(p3 >> 6) * DIM + lane];
            atomicAdd(&acc[(p0 & 63) * DIM + lane], v0 * x0);
            atomicAdd(&acc[(p1 & 63) * DIM + lane], v1 * x1);
            atomicAdd(&acc[(p2 & 63) * DIM + lane], v2 * x2);
            atomicAdd(&acc[(p3 & 63) * DIM + lane], v3 * x3);
        }
        for (; j < m; ++j) {
            const int   p = __shfl(e.x, j);
            const float v = __int_as_float(__shfl(e.y, j));
            atomicAdd(&acc[(p & 63) * DIM + lane],
                      v * src[(long)(p >> 6) * DIM + lane]);
        }
    }
}

// ---------------- Op1: s1 = 0.5*(A[i0]+A[i1]) @ s0 ----------------
__global__ __launch_bounds__(256) void op1_kernel(
    const float* __restrict__ s0, float* __restrict__ s1,
    const int2* __restrict__ bins, const int* __restrict__ cnt,
    const int* __restrict__ idx) {
    __shared__ float acc[64 * DIM];
    const int tid = threadIdx.x, lane = tid & 63, wave = tid >> 6;
    const int b = blockIdx.x;
    for (int i = tid; i < 64 * DIM; i += 256) acc[i] = 0.0f;
    __syncthreads();
    accum_seg(s0, bins, cnt, idx[0] * NB + b, acc, wave, lane);
    accum_seg(s0, bins, cnt, idx[1] * NB + b, acc, wave, lane);
    __syncthreads();
    const int row0 = b * 64;
    #pragma unroll
    for (int k = 0; k < 16; ++k) {
        const int rl = wave + k * 4;
        const int r  = row0 + rl;
        if (r < N_NODES)
            s1[(long)r * DIM + lane] = 0.5f * acc[rl * DIM + lane];
    }
}

// ---- Op2+Op3+LN+GELU: out = gelu(LN(0.5*(seq@s1) + 0.5*(res@s0))) ----
__global__ __launch_bounds__(256) void op23_kernel(
    const float* __restrict__ s1, const float* __restrict__ s0,
    float* __restrict__ out, const int2* __restrict__ bins,
    const int* __restrict__ cnt, const int* __restrict__ iseq2,
    const int* __restrict__ ires, const float* __restrict__ gamma,
    const float* __restrict__ beta) {
    __shared__ float acc[64 * DIM];
    const int tid = threadIdx.x, lane = tid & 63, wave = tid >> 6;
    const int b = blockIdx.x;
    for (int i = tid; i < 64 * DIM; i += 256) acc[i] = 0.0f;
    __syncthreads();
    accum_seg(s1, bins, cnt, iseq2[0] * NB + b, acc, wave, lane);
    accum_seg(s1, bins, cnt, iseq2[1] * NB + b, acc, wave, lane);
    accum_seg(s0, bins, cnt, ires[0] * NB + b, acc, wave, lane);
    accum_seg(s0, bins, cnt, ires[1] * NB + b, acc, wave, lane);
    __syncthreads();
    const float gm = gamma[lane], bt = beta[lane];
    const int row0 = b * 64;
    #pragma unroll
    for (int k = 0; k < 16; ++k) {
        const int rl = wave + k * 4;
        const int r  = row0 + rl;
        if (r >= N_NODES) continue;
        const float t = 0.5f * acc[rl * DIM + lane];
        float s = t, s2 = t * t;
        #pragma unroll
        for (int off = 32; off > 0; off >>= 1) {
            s  += __shfl_xor(s, off);
            s2 += __shfl_xor(s2, off);
        }
        const float mu  = s * (1.0f / DIM);
        const float var = s2 * (1.0f / DIM) - mu * mu;
        const float inv = rsqrtf(var + 1e-5f);
        const float y = (t - mu) * inv * gm + bt;
        const float g = 0.5f * y * (1.0f + erff(y * 0.70710678118654752f));
        out[(long)r * DIM + lane] = g;
    }
}

extern "C" void kernel_launch(void* const* d_in, const int* in_sizes, int n_in,
                              void* d_out, int out_size, void* d_ws, size_t ws_size,
                              hipStream_t stream) {
    const float* x     = (const float*)d_in[0];
    const float* W     = (const float*)d_in[1];
    const float* b     = (const float*)d_in[2];
    const int*   rows  = (const int*)d_in[3];
    const int*   cols  = (const int*)d_in[4];
    const float* vals  = (const float*)d_in[5];
    const float* gamma = (const float*)d_in[6];
    const float* beta  = (const float*)d_in[7];
    const int*   idxes_seq = (const int*)d_in[8];   // [2,2] flat
    const int*   idxes_res = (const int*)d_in[9];   // [1,2] flat
    float* out = (float*)d_out;

    // workspace layout
    int2*  bins = (int2*)d_ws;                                  // 4*NB*CAP*8 = 64 MB
    float* s0   = (float*)(bins + (size_t)N_ADJ * NB * CAP);    // 25.6 MB
    float* s1   = s0 + (size_t)N_NODES * DIM;                   // 25.6 MB
    int*   cnt  = (int*)(s1 + (size_t)N_NODES * DIM);           // 4*NB ints

    hipMemsetAsync(cnt, 0, (size_t)N_ADJ * NB * sizeof(int), stream);

    gemm_kernel<<<N_NODES / 16, 256, 0, stream>>>(x, W, b, s0);

    dim3 egrid(E_EDGES / 256, N_ADJ);
    bin_kernel<<<egrid, 256, 0, stream>>>(rows, cols, vals, cnt, bins);

    op1_kernel<<<NB, 256, 0, stream>>>(s0, s1, bins, cnt, idxes_seq);
    op23_kernel<<<NB, 256, 0, stream>>>(s1, s0, out, bins, cnt,
                                        idxes_seq + 2, idxes_res, gamma, beta);
}

// Round 5
// 652.465 us; speedup vs baseline: 7.3902x; 7.3902x over previous
//
#include <hip/hip_runtime.h>
#include <math.h>

#define N_NODES 100000
#define DIM 64
#define E_EDGES 1600000
#define N_ADJ 4
#define NB 1563              // ceil(100000/64) buckets of 64 rows
#define NBTOT (N_ADJ * NB)   // 6252
#define P1_BLK 1024
#define P1_CHUNK 12800
#define P1_GRIDX 125         // 125 * 12800 = 1.6M
#define SORT_STAGE 4096      // per-bucket LDS stage; mean load 1024, +96 sigma

// ---------------- GEMM: s0 = x @ W + b ----------------
__global__ __launch_bounds__(256) void gemm_kernel(
    const float* __restrict__ x, const float* __restrict__ W,
    const float* __restrict__ b, float* __restrict__ h) {
    __shared__ float Ws[DIM * DIM];
    __shared__ float xs[16 * DIM];
    const int tid = threadIdx.x;
    const long row0 = (long)blockIdx.x * 16;
    for (int i = tid; i < DIM * DIM; i += 256) Ws[i] = W[i];
    for (int i = tid; i < 16 * DIM; i += 256) xs[i] = x[row0 * DIM + i];
    __syncthreads();
    const int lane = tid & 63;
    const int grp  = tid >> 6;
    const float bias = b[lane];
    #pragma unroll
    for (int rr = 0; rr < 4; ++rr) {
        const int r = grp * 4 + rr;
        float acc = bias;
        #pragma unroll
        for (int k = 0; k < DIM; ++k)
            acc += xs[r * DIM + k] * Ws[k * DIM + lane];
        h[(row0 + r) * DIM + lane] = acc;
    }
}

// ---- hist: LDS-aggregated bucket counts -> gcnt ----
__global__ __launch_bounds__(1024) void hist_kernel(
    const int* __restrict__ rows, int* __restrict__ gcnt) {
    __shared__ int h[NB];
    const int tid = threadIdx.x;
    const int a   = blockIdx.y;
    const long e0 = (long)a * E_EDGES + (long)blockIdx.x * P1_CHUNK;
    for (int i = tid; i < NB; i += P1_BLK) h[i] = 0;
    __syncthreads();
    for (int i = tid; i < P1_CHUNK; i += P1_BLK)
        atomicAdd(&h[rows[e0 + i] >> 6], 1);
    __syncthreads();
    for (int bk = tid; bk < NB; bk += P1_BLK) {
        const int c = h[bk];
        if (c) atomicAdd(&gcnt[a * NB + bk], c);
    }
}

// ---- scan: exact exclusive scan of 6252 bucket counts (1 block) ----
__global__ __launch_bounds__(1024) void scan_kernel(
    const int* __restrict__ gcnt, int* __restrict__ bbase,
    int* __restrict__ cursor) {
    __shared__ int wsum[16];
    const int tid = threadIdx.x, lane = tid & 63, wave = tid >> 6;
    int pre[7];
    int tsum = 0;
    #pragma unroll
    for (int k = 0; k < 7; ++k) {
        const int idx = tid * 7 + k;
        const int v = (idx < NBTOT) ? gcnt[idx] : 0;
        pre[k] = tsum;
        tsum += v;
    }
    int incl = tsum;
    #pragma unroll
    for (int o = 1; o < 64; o <<= 1) {
        const int t = __shfl_up(incl, o);
        if (lane >= o) incl += t;
    }
    if (lane == 63) wsum[wave] = incl;
    __syncthreads();
    if (tid == 0) {
        int run = 0;
        #pragma unroll
        for (int w = 0; w < 16; ++w) { const int t = wsum[w]; wsum[w] = run; run += t; }
    }
    __syncthreads();
    const int texcl = incl - tsum + wsum[wave];
    #pragma unroll
    for (int k = 0; k < 7; ++k) {
        const int idx = tid * 7 + k;
        if (idx < NBTOT) {
            const int v = texcl + pre[k];
            bbase[idx]  = v;
            cursor[idx] = v;
        }
    }
    if (tid == 0) bbase[NBTOT] = N_ADJ * E_EDGES;
}

// ---- place: reserve per-(block,bucket) runs, pack edges ----
__global__ __launch_bounds__(1024) void place_kernel(
    const int* __restrict__ rows, const int* __restrict__ cols,
    const float* __restrict__ vals, int* __restrict__ cursor,
    int2* __restrict__ bins) {
    __shared__ int h[NB];
    const int tid = threadIdx.x;
    const int a   = blockIdx.y;
    const long e0 = (long)a * E_EDGES + (long)blockIdx.x * P1_CHUNK;
    for (int i = tid; i < NB; i += P1_BLK) h[i] = 0;
    __syncthreads();
    for (int i = tid; i < P1_CHUNK; i += P1_BLK)
        atomicAdd(&h[rows[e0 + i] >> 6], 1);
    __syncthreads();
    for (int bk = tid; bk < NB; bk += P1_BLK) {
        const int c = h[bk];
        if (c) h[bk] = atomicAdd(&cursor[a * NB + bk], c);  // abs base of run
    }
    __syncthreads();
    for (int i = tid; i < P1_CHUNK; i += P1_BLK) {
        const int r  = rows[e0 + i];
        const int bk = r >> 6;
        const int slot = atomicAdd(&h[bk], 1);              // absolute bins index
        bins[slot] = make_int2((cols[e0 + i] << 6) | (r & 63),
                               __float_as_int(vals[e0 + i]));
    }
}

// ---- sort: per-bucket counting sort by row&63, emit per-row (start,count) ----
__global__ __launch_bounds__(256) void sort_kernel(
    int2* __restrict__ bins, const int* __restrict__ bbase,
    int2* __restrict__ rowinfo) {
    __shared__ int2 stage[SORT_STAGE];
    __shared__ int h[64], off[64], cur[64];
    const int tid = threadIdx.x;
    const int a   = blockIdx.x / NB;
    const int bk  = blockIdx.x % NB;
    const int p0  = bbase[blockIdx.x];
    const int n   = min(bbase[blockIdx.x + 1] - p0, SORT_STAGE);

    if (tid < 64) h[tid] = 0;
    __syncthreads();
    for (int i = tid; i < n; i += 256) {
        const int2 e = bins[p0 + i];
        stage[i] = e;
        atomicAdd(&h[e.x & 63], 1);
    }
    __syncthreads();
    if (tid < 64) {
        const int v = h[tid];
        int incl = v;
        #pragma unroll
        for (int o = 1; o < 64; o <<= 1) {
            const int t = __shfl_up(incl, o);
            if (tid >= o) incl += t;
        }
        off[tid] = incl - v;
        cur[tid] = incl - v;
    }
    __syncthreads();
    for (int i = tid; i < n; i += 256) {
        const int2 e = stage[i];
        const int rank = atomicAdd(&cur[e.x & 63], 1);
        bins[p0 + rank] = e;
    }
    if (tid < 64) {
        const int row = bk * 64 + tid;
        if (row < N_NODES)
            rowinfo[a * N_NODES + row] = make_int2(p0 + off[tid], h[tid]);
    }
}

// ---------------- Pull gather (R2-verified structure) ----------------
__device__ __forceinline__ float gather_segs(
    const float* __restrict__ src, const int2* __restrict__ bins,
    const int2* __restrict__ rowinfo, const int* __restrict__ idx,
    int row, int lane) {
    float acc = 0.0f;
    #pragma unroll
    for (int s = 0; s < 2; ++s) {
        const int a = idx[s];
        const int2 info = rowinfo[a * N_NODES + row];
        const int p0 = info.x;
        const int p1 = info.x + info.y;
        for (int j0 = p0; j0 < p1; j0 += 64) {
            const int nj = min(64, p1 - j0);
            int2 e = make_int2(0, 0);
            if (lane < nj) e = bins[j0 + lane];
            int j = 0;
            for (; j + 4 <= nj; j += 4) {
                const int   c0 = __shfl(e.x, j + 0) >> 6;
                const int   c1 = __shfl(e.x, j + 1) >> 6;
                const int   c2 = __shfl(e.x, j + 2) >> 6;
                const int   c3 = __shfl(e.x, j + 3) >> 6;
                const float v0 = __int_as_float(__shfl(e.y, j + 0));
                const float v1 = __int_as_float(__shfl(e.y, j + 1));
                const float v2 = __int_as_float(__shfl(e.y, j + 2));
                const float v3 = __int_as_float(__shfl(e.y, j + 3));
                const float x0 = src[(long)c0 * DIM + lane];
                const float x1 = src[(long)c1 * DIM + lane];
                const float x2 = src[(long)c2 * DIM + lane];
                const float x3 = src[(long)c3 * DIM + lane];
                acc = fmaf(v0, x0, acc);
                acc = fmaf(v1, x1, acc);
                acc = fmaf(v2, x2, acc);
                acc = fmaf(v3, x3, acc);
            }
            for (; j < nj; ++j) {
                const int   c = __shfl(e.x, j) >> 6;
                const float v = __int_as_float(__shfl(e.y, j));
                acc = fmaf(v, src[(long)c * DIM + lane], acc);
            }
        }
    }
    return acc;
}

__global__ __launch_bounds__(256) void gather_op_kernel(
    const float* __restrict__ src, float* __restrict__ dst,
    const int2* __restrict__ bins, const int2* __restrict__ rowinfo,
    const int* __restrict__ idx) {
    const int lane = threadIdx.x & 63;
    const int row  = blockIdx.x * 4 + (threadIdx.x >> 6);
    const float acc = gather_segs(src, bins, rowinfo, idx, row, lane);
    dst[(long)row * DIM + lane] = 0.5f * acc;
}

__global__ __launch_bounds__(256) void fused_op_ln_gelu_kernel(
    const float* __restrict__ s1, const float* __restrict__ s0,
    float* __restrict__ out, const int2* __restrict__ bins,
    const int2* __restrict__ rowinfo, const int* __restrict__ idx_seq1,
    const int* __restrict__ idx_res, const float* __restrict__ gamma,
    const float* __restrict__ beta) {
    const int lane = threadIdx.x & 63;
    const int row  = blockIdx.x * 4 + (threadIdx.x >> 6);
    const float a1 = gather_segs(s1, bins, rowinfo, idx_seq1, row, lane);
    const float a0 = gather_segs(s0, bins, rowinfo, idx_res,  row, lane);
    const float t = 0.5f * a1 + 0.5f * a0;
    float s = t, s2 = t * t;
    #pragma unroll
    for (int off = 32; off > 0; off >>= 1) {
        s  += __shfl_xor(s, off);
        s2 += __shfl_xor(s2, off);
    }
    const float mu  = s * (1.0f / DIM);
    const float var = s2 * (1.0f / DIM) - mu * mu;
    const float inv = rsqrtf(var + 1e-5f);
    const float y = (t - mu) * inv * gamma[lane] + beta[lane];
    const float g = 0.5f * y * (1.0f + erff(y * 0.70710678118654752f));
    out[(long)row * DIM + lane] = g;
}

extern "C" void kernel_launch(void* const* d_in, const int* in_sizes, int n_in,
                              void* d_out, int out_size, void* d_ws, size_t ws_size,
                              hipStream_t stream) {
    const float* x     = (const float*)d_in[0];
    const float* W     = (const float*)d_in[1];
    const float* b     = (const float*)d_in[2];
    const int*   rows  = (const int*)d_in[3];
    const int*   cols  = (const int*)d_in[4];
    const float* vals  = (const float*)d_in[5];
    const float* gamma = (const float*)d_in[6];
    const float* beta  = (const float*)d_in[7];
    const int*   idxes_seq = (const int*)d_in[8];   // [2,2] flat
    const int*   idxes_res = (const int*)d_in[9];   // [1,2] flat
    float* out = (float*)d_out;

    // workspace layout: ~105.7 MB total (< R2's proven 115.25 MB use)
    int2*  bins    = (int2*)d_ws;                                // 4E int2 = 51.2 MB
    float* s0      = (float*)(bins + (size_t)N_ADJ * E_EDGES);   // 25.6 MB
    float* s1      = s0 + (size_t)N_NODES * DIM;                 // 25.6 MB
    int2*  rowinfo = (int2*)(s1 + (size_t)N_NODES * DIM);        // 3.2 MB
    int*   gcnt    = (int*)(rowinfo + (size_t)N_ADJ * N_NODES);  // 6252 ints
    int*   bbase   = gcnt + NBTOT;                               // 6253 ints
    int*   cursor  = bbase + NBTOT + 1;                          // 6252 ints

    hipMemsetAsync(gcnt, 0, (size_t)NBTOT * sizeof(int), stream);

    gemm_kernel<<<N_NODES / 16, 256, 0, stream>>>(x, W, b, s0);

    dim3 egrid(P1_GRIDX, N_ADJ);
    hist_kernel <<<egrid, P1_BLK, 0, stream>>>(rows, gcnt);
    scan_kernel <<<1, P1_BLK, 0, stream>>>(gcnt, bbase, cursor);
    place_kernel<<<egrid, P1_BLK, 0, stream>>>(rows, cols, vals, cursor, bins);
    sort_kernel <<<NBTOT, 256, 0, stream>>>(bins, bbase, rowinfo);

    // s1 = 0.5*(A[i0]+A[i1]) @ s0
    gather_op_kernel<<<N_NODES / 4, 256, 0, stream>>>(s0, s1, bins, rowinfo, idxes_seq);
    // out = gelu(LN(0.5*(A[i2]+A[i3])@s1 + 0.5*(A[r0]+A[r1])@s0))
    fused_op_ln_gelu_kernel<<<N_NODES / 4, 256, 0, stream>>>(
        s1, s0, out, bins, rowinfo, idxes_seq + 2, idxes_res, gamma, beta);
}

// Round 6
// 600.326 us; speedup vs baseline: 8.0320x; 1.0869x over previous
//
#include <hip/hip_runtime.h>
#include <hip/hip_bf16.h>
#include <math.h>

#define N_NODES 100000
#define DIM 64
#define E_EDGES 1600000
#define N_ADJ 4
#define NB 1563              // ceil(100000/64) buckets of 64 rows
#define NBTOT (N_ADJ * NB)   // 6252
#define P1_BLK 1024
#define P1_CHUNK 12800
#define P1_GRIDX 125         // 125 * 12800 = 1.6M
#define SORT_STAGE 4096      // per-bucket LDS stage; mean load 1024

typedef unsigned short u16;
typedef unsigned int u32;

// ---------------- GEMM: s0 = bf16(x @ W + b) ----------------
__global__ __launch_bounds__(256) void gemm_kernel(
    const float* __restrict__ x, const float* __restrict__ W,
    const float* __restrict__ b, u16* __restrict__ h) {
    __shared__ float Ws[DIM * DIM];
    __shared__ float xs[16 * DIM];
    const int tid = threadIdx.x;
    const long row0 = (long)blockIdx.x * 16;
    for (int i = tid; i < DIM * DIM; i += 256) Ws[i] = W[i];
    for (int i = tid; i < 16 * DIM; i += 256) xs[i] = x[row0 * DIM + i];
    __syncthreads();
    const int lane = tid & 63;
    const int grp  = tid >> 6;
    const float bias = b[lane];
    #pragma unroll
    for (int rr = 0; rr < 4; ++rr) {
        const int r = grp * 4 + rr;
        float acc = bias;
        #pragma unroll
        for (int k = 0; k < DIM; ++k)
            acc += xs[r * DIM + k] * Ws[k * DIM + lane];
        __hip_bfloat16 hb = __float2bfloat16(acc);
        h[(row0 + r) * DIM + lane] = *(u16*)&hb;
    }
}

// ---- hist: LDS-aggregated bucket counts -> gcnt ----
__global__ __launch_bounds__(1024) void hist_kernel(
    const int* __restrict__ rows, int* __restrict__ gcnt) {
    __shared__ int h[NB];
    const int tid = threadIdx.x;
    const int a   = blockIdx.y;
    const long e0 = (long)a * E_EDGES + (long)blockIdx.x * P1_CHUNK;
    for (int i = tid; i < NB; i += P1_BLK) h[i] = 0;
    __syncthreads();
    for (int i = tid; i < P1_CHUNK; i += P1_BLK)
        atomicAdd(&h[rows[e0 + i] >> 6], 1);
    __syncthreads();
    for (int bk = tid; bk < NB; bk += P1_BLK) {
        const int c = h[bk];
        if (c) atomicAdd(&gcnt[a * NB + bk], c);
    }
}

// ---- scan: exact exclusive scan of 6252 bucket counts (1 block) ----
__global__ __launch_bounds__(1024) void scan_kernel(
    const int* __restrict__ gcnt, int* __restrict__ bbase,
    int* __restrict__ cursor) {
    __shared__ int wsum[16];
    const int tid = threadIdx.x, lane = tid & 63, wave = tid >> 6;
    int pre[7];
    int tsum = 0;
    #pragma unroll
    for (int k = 0; k < 7; ++k) {
        const int idx = tid * 7 + k;
        const int v = (idx < NBTOT) ? gcnt[idx] : 0;
        pre[k] = tsum;
        tsum += v;
    }
    int incl = tsum;
    #pragma unroll
    for (int o = 1; o < 64; o <<= 1) {
        const int t = __shfl_up(incl, o);
        if (lane >= o) incl += t;
    }
    if (lane == 63) wsum[wave] = incl;
    __syncthreads();
    if (tid == 0) {
        int run = 0;
        #pragma unroll
        for (int w = 0; w < 16; ++w) { const int t = wsum[w]; wsum[w] = run; run += t; }
    }
    __syncthreads();
    const int texcl = incl - tsum + wsum[wave];
    #pragma unroll
    for (int k = 0; k < 7; ++k) {
        const int idx = tid * 7 + k;
        if (idx < NBTOT) {
            const int v = texcl + pre[k];
            bbase[idx]  = v;
            cursor[idx] = v;
        }
    }
    if (tid == 0) bbase[NBTOT] = N_ADJ * E_EDGES;
}

// ---- place: reserve per-(block,bucket) runs, pack edges ----
__global__ __launch_bounds__(1024) void place_kernel(
    const int* __restrict__ rows, const int* __restrict__ cols,
    const float* __restrict__ vals, int* __restrict__ cursor,
    int2* __restrict__ bins) {
    __shared__ int h[NB];
    const int tid = threadIdx.x;
    const int a   = blockIdx.y;
    const long e0 = (long)a * E_EDGES + (long)blockIdx.x * P1_CHUNK;
    for (int i = tid; i < NB; i += P1_BLK) h[i] = 0;
    __syncthreads();
    for (int i = tid; i < P1_CHUNK; i += P1_BLK)
        atomicAdd(&h[rows[e0 + i] >> 6], 1);
    __syncthreads();
    for (int bk = tid; bk < NB; bk += P1_BLK) {
        const int c = h[bk];
        if (c) h[bk] = atomicAdd(&cursor[a * NB + bk], c);  // abs base of run
    }
    __syncthreads();
    for (int i = tid; i < P1_CHUNK; i += P1_BLK) {
        const int r  = rows[e0 + i];
        const int bk = r >> 6;
        const int slot = atomicAdd(&h[bk], 1);              // absolute bins index
        bins[slot] = make_int2((cols[e0 + i] << 6) | (r & 63),
                               __float_as_int(vals[e0 + i]));
    }
}

// ---- sort: per-bucket counting sort by row&63, emit per-row (start,count) ----
__global__ __launch_bounds__(256) void sort_kernel(
    int2* __restrict__ bins, const int* __restrict__ bbase,
    int2* __restrict__ rowinfo) {
    __shared__ int2 stage[SORT_STAGE];
    __shared__ int h[64], off[64], cur[64];
    const int tid = threadIdx.x;
    const int a   = blockIdx.x / NB;
    const int bk  = blockIdx.x % NB;
    const int p0  = bbase[blockIdx.x];
    const int n   = min(bbase[blockIdx.x + 1] - p0, SORT_STAGE);

    if (tid < 64) h[tid] = 0;
    __syncthreads();
    for (int i = tid; i < n; i += 256) {
        const int2 e = bins[p0 + i];
        stage[i] = e;
        atomicAdd(&h[e.x & 63], 1);
    }
    __syncthreads();
    if (tid < 64) {
        const int v = h[tid];
        int incl = v;
        #pragma unroll
        for (int o = 1; o < 64; o <<= 1) {
            const int t = __shfl_up(incl, o);
            if (tid >= o) incl += t;
        }
        off[tid] = incl - v;
        cur[tid] = incl - v;
    }
    __syncthreads();
    for (int i = tid; i < n; i += 256) {
        const int2 e = stage[i];
        const int rank = atomicAdd(&cur[e.x & 63], 1);
        bins[p0 + rank] = e;
    }
    if (tid < 64) {
        const int row = bk * 64 + tid;
        if (row < N_NODES)
            rowinfo[a * N_NODES + row] = make_int2(p0 + off[tid], h[tid]);
    }
}

// ---------------- Pull gather, bf16 src, 16 lanes/edge ----------------
// Wave = 1 row. Lane layout: grp = lane>>4 (edge slot), sub = lane&15 (4 dims).
// Returns per-lane float4 PARTIAL (sum over this group's edges); caller must
// reduce across groups with shfl_xor(16), shfl_xor(32).
__device__ __forceinline__ float4 gather_segs(
    const u16* __restrict__ src, const int2* __restrict__ bins,
    const int2* __restrict__ rowinfo, const int* __restrict__ idx,
    int row, int lane) {
    const int grp = lane >> 4;
    const int sub = lane & 15;
    float4 acc = make_float4(0.f, 0.f, 0.f, 0.f);
    #pragma unroll
    for (int s = 0; s < 2; ++s) {
        const int a = idx[s];
        const int2 info = rowinfo[a * N_NODES + row];
        const int p0 = info.x;
        const int p1 = info.x + info.y;
        for (int j0 = p0; j0 < p1; j0 += 64) {
            const int nj = min(64, p1 - j0);
            int2 e = make_int2(0, 0);
            if (lane < nj) e = bins[j0 + lane];
            for (int j = 0; j < nj; j += 4) {
                // group g consumes edge j+g; lanes >= nj hold e=(0,0) -> v=0
                const int   cv = __shfl(e.x, j + grp);
                const float v  = __int_as_float(__shfl(e.y, j + grp));
                const int   c  = cv >> 6;
                const uint2 w  = *(const uint2*)(src + (long)c * DIM + sub * 4);
                const float x0 = __int_as_float(w.x << 16);
                const float x1 = __int_as_float(w.x & 0xffff0000u);
                const float x2 = __int_as_float(w.y << 16);
                const float x3 = __int_as_float(w.y & 0xffff0000u);
                acc.x = fmaf(v, x0, acc.x);
                acc.y = fmaf(v, x1, acc.y);
                acc.z = fmaf(v, x2, acc.z);
                acc.w = fmaf(v, x3, acc.w);
            }
        }
    }
    return acc;
}

__device__ __forceinline__ float4 reduce_groups(float4 t) {
    t.x += __shfl_xor(t.x, 16); t.y += __shfl_xor(t.y, 16);
    t.z += __shfl_xor(t.z, 16); t.w += __shfl_xor(t.w, 16);
    t.x += __shfl_xor(t.x, 32); t.y += __shfl_xor(t.y, 32);
    t.z += __shfl_xor(t.z, 32); t.w += __shfl_xor(t.w, 32);
    return t;
}

// s1 = bf16(0.5*(A[i0]+A[i1]) @ s0)
__global__ __launch_bounds__(256) void gather_op_kernel(
    const u16* __restrict__ src, u16* __restrict__ dst,
    const int2* __restrict__ bins, const int2* __restrict__ rowinfo,
    const int* __restrict__ idx) {
    const int lane = threadIdx.x & 63;
    const int row  = blockIdx.x * 4 + (threadIdx.x >> 6);
    float4 t = gather_segs(src, bins, rowinfo, idx, row, lane);
    t = reduce_groups(t);
    if (lane < 16) {
        const int sub = lane;
        __hip_bfloat16 b0 = __float2bfloat16(0.5f * t.x);
        __hip_bfloat16 b1 = __float2bfloat16(0.5f * t.y);
        __hip_bfloat16 b2 = __float2bfloat16(0.5f * t.z);
        __hip_bfloat16 b3 = __float2bfloat16(0.5f * t.w);
        const u32 lo = (u32)(*(u16*)&b0) | ((u32)(*(u16*)&b1) << 16);
        const u32 hi = (u32)(*(u16*)&b2) | ((u32)(*(u16*)&b3) << 16);
        *(uint2*)(dst + (long)row * DIM + sub * 4) = make_uint2(lo, hi);
    }
}

// out = gelu(LN(0.5*(seq@s1) + 0.5*(res@s0)))
__global__ __launch_bounds__(256) void fused_op_ln_gelu_kernel(
    const u16* __restrict__ s1, const u16* __restrict__ s0,
    float* __restrict__ out, const int2* __restrict__ bins,
    const int2* __restrict__ rowinfo, const int* __restrict__ idx_seq1,
    const int* __restrict__ idx_res, const float* __restrict__ gamma,
    const float* __restrict__ beta) {
    const int lane = threadIdx.x & 63;
    const int row  = blockIdx.x * 4 + (threadIdx.x >> 6);
    const float4 a1 = gather_segs(s1, bins, rowinfo, idx_seq1, row, lane);
    const float4 a0 = gather_segs(s0, bins, rowinfo, idx_res,  row, lane);
    float4 t = make_float4(0.5f * (a1.x + a0.x), 0.5f * (a1.y + a0.y),
                           0.5f * (a1.z + a0.z), 0.5f * (a1.w + a0.w));
    t = reduce_groups(t);
    // LN stats across 64 dims: horizontal then across the 16 subs
    float s  = t.x + t.y + t.z + t.w;
    float s2 = t.x * t.x + t.y * t.y + t.z * t.z + t.w * t.w;
    #pragma unroll
    for (int off = 8; off > 0; off >>= 1) {
        s  += __shfl_xor(s, off);
        s2 += __shfl_xor(s2, off);
    }
    const float mu  = s * (1.0f / DIM);
    const float var = s2 * (1.0f / DIM) - mu * mu;
    const float inv = rsqrtf(var + 1e-5f);
    if (lane < 16) {
        const int sub = lane;
        const float4 gm = ((const float4*)gamma)[sub];
        const float4 bt = ((const float4*)beta)[sub];
        float4 y;
        y.x = (t.x - mu) * inv * gm.x + bt.x;
        y.y = (t.y - mu) * inv * gm.y + bt.y;
        y.z = (t.z - mu) * inv * gm.z + bt.z;
        y.w = (t.w - mu) * inv * gm.w + bt.w;
        float4 g;
        g.x = 0.5f * y.x * (1.0f + erff(y.x * 0.70710678118654752f));
        g.y = 0.5f * y.y * (1.0f + erff(y.y * 0.70710678118654752f));
        g.z = 0.5f * y.z * (1.0f + erff(y.z * 0.70710678118654752f));
        g.w = 0.5f * y.w * (1.0f + erff(y.w * 0.70710678118654752f));
        ((float4*)(out + (long)row * DIM))[sub] = g;
    }
}

extern "C" void kernel_launch(void* const* d_in, const int* in_sizes, int n_in,
                              void* d_out, int out_size, void* d_ws, size_t ws_size,
                              hipStream_t stream) {
    const float* x     = (const float*)d_in[0];
    const float* W     = (const float*)d_in[1];
    const float* b     = (const float*)d_in[2];
    const int*   rows  = (const int*)d_in[3];
    const int*   cols  = (const int*)d_in[4];
    const float* vals  = (const float*)d_in[5];
    const float* gamma = (const float*)d_in[6];
    const float* beta  = (const float*)d_in[7];
    const int*   idxes_seq = (const int*)d_in[8];   // [2,2] flat
    const int*   idxes_res = (const int*)d_in[9];   // [1,2] flat
    float* out = (float*)d_out;

    // workspace layout: ~80 MB total
    int2*  bins    = (int2*)d_ws;                                // 4E int2 = 51.2 MB
    u16*   s0      = (u16*)(bins + (size_t)N_ADJ * E_EDGES);     // 12.8 MB bf16
    u16*   s1      = s0 + (size_t)N_NODES * DIM;                 // 12.8 MB bf16
    int2*  rowinfo = (int2*)(s1 + (size_t)N_NODES * DIM);        // 3.2 MB
    int*   gcnt    = (int*)(rowinfo + (size_t)N_ADJ * N_NODES);  // 6252 ints
    int*   bbase   = gcnt + NBTOT;                               // 6253 ints
    int*   cursor  = bbase + NBTOT + 1;                          // 6252 ints

    hipMemsetAsync(gcnt, 0, (size_t)NBTOT * sizeof(int), stream);

    gemm_kernel<<<N_NODES / 16, 256, 0, stream>>>(x, W, b, s0);

    dim3 egrid(P1_GRIDX, N_ADJ);
    hist_kernel <<<egrid, P1_BLK, 0, stream>>>(rows, gcnt);
    scan_kernel <<<1, P1_BLK, 0, stream>>>(gcnt, bbase, cursor);
    place_kernel<<<egrid, P1_BLK, 0, stream>>>(rows, cols, vals, cursor, bins);
    sort_kernel <<<NBTOT, 256, 0, stream>>>(bins, bbase, rowinfo);

    // s1 = 0.5*(A[i0]+A[i1]) @ s0
    gather_op_kernel<<<N_NODES / 4, 256, 0, stream>>>(s0, s1, bins, rowinfo, idxes_seq);
    // out = gelu(LN(0.5*(A[i2]+A[i3])@s1 + 0.5*(A[r0]+A[r1])@s0))
    fused_op_ln_gelu_kernel<<<N_NODES / 4, 256, 0, stream>>>(
        s1, s0, out, bins, rowinfo, idxes_seq + 2, idxes_res, gamma, beta);
}

// Round 7
// 510.065 us; speedup vs baseline: 9.4534x; 1.1770x over previous
//
#include <hip/hip_runtime.h>
#include <hip/hip_bf16.h>
#include <math.h>

#define N_NODES 100000
#define DIM 64
#define E_EDGES 1600000
#define N_ADJ 4
#define NB 1563              // ceil(100000/64) buckets of 64 rows
#define NBTOT (N_ADJ * NB)   // 6252
#define P1_BLK 1024
#define P1_CHUNK 12800
#define P1_GRIDX 125         // 125 * 12800 = 1.6M
#define SORT_STAGE 4096      // per-bucket LDS stage; mean load 1024

typedef unsigned short u16;
typedef unsigned int u32;

// ---- used-adjacency mask from device-side idxes ----
__global__ void mask_kernel(const int* __restrict__ iseq,
                            const int* __restrict__ ires,
                            int* __restrict__ used) {
    if (threadIdx.x == 0) {
        used[0] = used[1] = used[2] = used[3] = 0;
        used[iseq[0]] = 1; used[iseq[1]] = 1;
        used[iseq[2]] = 1; used[iseq[3]] = 1;
        used[ires[0]] = 1; used[ires[1]] = 1;
    }
}

// ---------------- GEMM: s0 = bf16(x @ W + b) ----------------
__global__ __launch_bounds__(256) void gemm_kernel(
    const float* __restrict__ x, const float* __restrict__ W,
    const float* __restrict__ b, u16* __restrict__ h) {
    __shared__ float Ws[DIM * DIM];
    __shared__ float xs[16 * DIM];
    const int tid = threadIdx.x;
    const long row0 = (long)blockIdx.x * 16;
    for (int i = tid; i < DIM * DIM; i += 256) Ws[i] = W[i];
    for (int i = tid; i < 16 * DIM; i += 256) xs[i] = x[row0 * DIM + i];
    __syncthreads();
    const int lane = tid & 63;
    const int grp  = tid >> 6;
    const float bias = b[lane];
    #pragma unroll
    for (int rr = 0; rr < 4; ++rr) {
        const int r = grp * 4 + rr;
        float acc = bias;
        #pragma unroll
        for (int k = 0; k < DIM; ++k)
            acc += xs[r * DIM + k] * Ws[k * DIM + lane];
        __hip_bfloat16 hb = __float2bfloat16(acc);
        h[(row0 + r) * DIM + lane] = *(u16*)&hb;
    }
}

// ---- hist: LDS-aggregated bucket counts -> gcnt ----
__global__ __launch_bounds__(1024) void hist_kernel(
    const int* __restrict__ rows, int* __restrict__ gcnt,
    const int* __restrict__ used) {
    __shared__ int h[NB];
    const int a = blockIdx.y;
    if (!used[a]) return;
    const int tid = threadIdx.x;
    const long e0 = (long)a * E_EDGES + (long)blockIdx.x * P1_CHUNK;
    for (int i = tid; i < NB; i += P1_BLK) h[i] = 0;
    __syncthreads();
    for (int i = tid; i < P1_CHUNK; i += P1_BLK)
        atomicAdd(&h[rows[e0 + i] >> 6], 1);
    __syncthreads();
    for (int bk = tid; bk < NB; bk += P1_BLK) {
        const int c = h[bk];
        if (c) atomicAdd(&gcnt[a * NB + bk], c);
    }
}

// ---- scan: exact exclusive scan of 6252 bucket counts (1 block) ----
__global__ __launch_bounds__(1024) void scan_kernel(
    const int* __restrict__ gcnt, int* __restrict__ bbase,
    int* __restrict__ cursor) {
    __shared__ int wsum[16];
    const int tid = threadIdx.x, lane = tid & 63, wave = tid >> 6;
    int pre[7];
    int tsum = 0;
    #pragma unroll
    for (int k = 0; k < 7; ++k) {
        const int idx = tid * 7 + k;
        const int v = (idx < NBTOT) ? gcnt[idx] : 0;
        pre[k] = tsum;
        tsum += v;
    }
    int incl = tsum;
    #pragma unroll
    for (int o = 1; o < 64; o <<= 1) {
        const int t = __shfl_up(incl, o);
        if (lane >= o) incl += t;
    }
    if (lane == 63) wsum[wave] = incl;
    __syncthreads();
    if (tid == 0) {
        int run = 0;
        #pragma unroll
        for (int w = 0; w < 16; ++w) { const int t = wsum[w]; wsum[w] = run; run += t; }
    }
    __syncthreads();
    const int texcl = incl - tsum + wsum[wave];
    #pragma unroll
    for (int k = 0; k < 7; ++k) {
        const int idx = tid * 7 + k;
        if (idx < NBTOT) {
            const int v = texcl + pre[k];
            bbase[idx]  = v;
            cursor[idx] = v;
        }
    }
    if (tid == 0) bbase[NBTOT] = N_ADJ * E_EDGES;
}

// ---- place: reserve per-(block,bucket) runs, pack edges ----
__global__ __launch_bounds__(1024) void place_kernel(
    const int* __restrict__ rows, const int* __restrict__ cols,
    const float* __restrict__ vals, int* __restrict__ cursor,
    int2* __restrict__ bins, const int* __restrict__ used) {
    __shared__ int h[NB];
    const int a = blockIdx.y;
    if (!used[a]) return;
    const int tid = threadIdx.x;
    const long e0 = (long)a * E_EDGES + (long)blockIdx.x * P1_CHUNK;
    for (int i = tid; i < NB; i += P1_BLK) h[i] = 0;
    __syncthreads();
    for (int i = tid; i < P1_CHUNK; i += P1_BLK)
        atomicAdd(&h[rows[e0 + i] >> 6], 1);
    __syncthreads();
    for (int bk = tid; bk < NB; bk += P1_BLK) {
        const int c = h[bk];
        if (c) h[bk] = atomicAdd(&cursor[a * NB + bk], c);  // abs base of run
    }
    __syncthreads();
    for (int i = tid; i < P1_CHUNK; i += P1_BLK) {
        const int r  = rows[e0 + i];
        const int bk = r >> 6;
        const int slot = atomicAdd(&h[bk], 1);              // absolute bins index
        bins[slot] = make_int2((cols[e0 + i] << 6) | (r & 63),
                               __float_as_int(vals[e0 + i]));
    }
}

// ---- sort: per-bucket counting sort by row&63, emit per-row (start,count) ----
__global__ __launch_bounds__(256) void sort_kernel(
    int2* __restrict__ bins, const int* __restrict__ bbase,
    int2* __restrict__ rowinfo, const int* __restrict__ used) {
    __shared__ int2 stage[SORT_STAGE];
    __shared__ int h[64], off[64], cur[64];
    const int a   = blockIdx.x / NB;
    if (!used[a]) return;
    const int tid = threadIdx.x;
    const int bk  = blockIdx.x % NB;
    const int p0  = bbase[blockIdx.x];
    const int n   = min(bbase[blockIdx.x + 1] - p0, SORT_STAGE);

    if (tid < 64) h[tid] = 0;
    __syncthreads();
    for (int i = tid; i < n; i += 256) {
        const int2 e = bins[p0 + i];
        stage[i] = e;
        atomicAdd(&h[e.x & 63], 1);
    }
    __syncthreads();
    if (tid < 64) {
        const int v = h[tid];
        int incl = v;
        #pragma unroll
        for (int o = 1; o < 64; o <<= 1) {
            const int t = __shfl_up(incl, o);
            if (tid >= o) incl += t;
        }
        off[tid] = incl - v;
        cur[tid] = incl - v;
    }
    __syncthreads();
    for (int i = tid; i < n; i += 256) {
        const int2 e = stage[i];
        const int rank = atomicAdd(&cur[e.x & 63], 1);
        bins[p0 + rank] = e;
    }
    if (tid < 64) {
        const int row = bk * 64 + tid;
        if (row < N_NODES)
            rowinfo[a * N_NODES + row] = make_int2(p0 + off[tid], h[tid]);
    }
}

// ---------------- Pull gather, bf16 src, 16 lanes/edge ----------------
// Wave = 1 row. grp = lane>>4 picks edge (4 in flight), sub = lane&15 -> 4 dims.
// Flat rotated loop: edge record prefetched one step ahead; same-address
// 16-lane broadcast load from bins (L1-sequential).
__device__ __forceinline__ void gather_pair(
    const u16* __restrict__ src, const int2* __restrict__ bins,
    const int2* __restrict__ rowinfo, const int* __restrict__ idx,
    int row, int grp, int sub, float4& acc) {
    #pragma unroll
    for (int s = 0; s < 2; ++s) {
        const int2 info = rowinfo[idx[s] * N_NODES + row];
        const int2* eb = bins + info.x;
        const int n = info.y;
        int2 e = make_int2(0, 0);
        if (grp < n) e = eb[grp];
        #pragma unroll 2
        for (int j = grp; j < n; j += 4) {
            const int jn = j + 4;
            const int2 en = eb[(jn < n) ? jn : j];   // prefetch next (clamped)
            const float v = __int_as_float(e.y);
            const int   c = e.x >> 6;
            const uint2 w = *(const uint2*)(src + (long)c * DIM + (sub << 2));
            acc.x = fmaf(v, __int_as_float(w.x << 16),         acc.x);
            acc.y = fmaf(v, __int_as_float(w.x & 0xffff0000u), acc.y);
            acc.z = fmaf(v, __int_as_float(w.y << 16),         acc.z);
            acc.w = fmaf(v, __int_as_float(w.y & 0xffff0000u), acc.w);
            e = en;
        }
    }
}

__device__ __forceinline__ float4 reduce_groups(float4 t) {
    t.x += __shfl_xor(t.x, 16); t.y += __shfl_xor(t.y, 16);
    t.z += __shfl_xor(t.z, 16); t.w += __shfl_xor(t.w, 16);
    t.x += __shfl_xor(t.x, 32); t.y += __shfl_xor(t.y, 32);
    t.z += __shfl_xor(t.z, 32); t.w += __shfl_xor(t.w, 32);
    return t;
}

// s1 = bf16(0.5*(A[i0]+A[i1]) @ s0)
__global__ __launch_bounds__(256) void gather_op_kernel(
    const u16* __restrict__ src, u16* __restrict__ dst,
    const int2* __restrict__ bins, const int2* __restrict__ rowinfo,
    const int* __restrict__ idx) {
    const int lane = threadIdx.x & 63;
    const int row  = blockIdx.x * 4 + (threadIdx.x >> 6);
    const int grp  = lane >> 4, sub = lane & 15;
    float4 t = make_float4(0.f, 0.f, 0.f, 0.f);
    gather_pair(src, bins, rowinfo, idx, row, grp, sub, t);
    t = reduce_groups(t);
    if (lane < 16) {
        __hip_bfloat16 b0 = __float2bfloat16(0.5f * t.x);
        __hip_bfloat16 b1 = __float2bfloat16(0.5f * t.y);
        __hip_bfloat16 b2 = __float2bfloat16(0.5f * t.z);
        __hip_bfloat16 b3 = __float2bfloat16(0.5f * t.w);
        const u32 lo = (u32)(*(u16*)&b0) | ((u32)(*(u16*)&b1) << 16);
        const u32 hi = (u32)(*(u16*)&b2) | ((u32)(*(u16*)&b3) << 16);
        *(uint2*)(dst + (long)row * DIM + lane * 4) = make_uint2(lo, hi);
    }
}

// out = gelu(LN(0.5*(seq@s1) + 0.5*(res@s0)))
__global__ __launch_bounds__(256) void fused_op_ln_gelu_kernel(
    const u16* __restrict__ s1, const u16* __restrict__ s0,
    float* __restrict__ out, const int2* __restrict__ bins,
    const int2* __restrict__ rowinfo, const int* __restrict__ idx_seq1,
    const int* __restrict__ idx_res, const float* __restrict__ gamma,
    const float* __restrict__ beta) {
    const int lane = threadIdx.x & 63;
    const int row  = blockIdx.x * 4 + (threadIdx.x >> 6);
    const int grp  = lane >> 4, sub = lane & 15;
    float4 t = make_float4(0.f, 0.f, 0.f, 0.f);
    gather_pair(s1, bins, rowinfo, idx_seq1, row, grp, sub, t);
    gather_pair(s0, bins, rowinfo, idx_res,  row, grp, sub, t);
    t.x *= 0.5f; t.y *= 0.5f; t.z *= 0.5f; t.w *= 0.5f;
    t = reduce_groups(t);
    float s  = t.x + t.y + t.z + t.w;
    float s2 = t.x * t.x + t.y * t.y + t.z * t.z + t.w * t.w;
    #pragma unroll
    for (int off = 8; off > 0; off >>= 1) {
        s  += __shfl_xor(s, off);
        s2 += __shfl_xor(s2, off);
    }
    const float mu  = s * (1.0f / DIM);
    const float var = s2 * (1.0f / DIM) - mu * mu;
    const float inv = rsqrtf(var + 1e-5f);
    if (lane < 16) {
        const float4 gm = ((const float4*)gamma)[lane];
        const float4 bt = ((const float4*)beta)[lane];
        float4 y;
        y.x = (t.x - mu) * inv * gm.x + bt.x;
        y.y = (t.y - mu) * inv * gm.y + bt.y;
        y.z = (t.z - mu) * inv * gm.z + bt.z;
        y.w = (t.w - mu) * inv * gm.w + bt.w;
        float4 g;
        g.x = 0.5f * y.x * (1.0f + erff(y.x * 0.70710678118654752f));
        g.y = 0.5f * y.y * (1.0f + erff(y.y * 0.70710678118654752f));
        g.z = 0.5f * y.z * (1.0f + erff(y.z * 0.70710678118654752f));
        g.w = 0.5f * y.w * (1.0f + erff(y.w * 0.70710678118654752f));
        ((float4*)(out + (long)row * DIM))[lane] = g;
    }
}

extern "C" void kernel_launch(void* const* d_in, const int* in_sizes, int n_in,
                              void* d_out, int out_size, void* d_ws, size_t ws_size,
                              hipStream_t stream) {
    const float* x     = (const float*)d_in[0];
    const float* W     = (const float*)d_in[1];
    const float* b     = (const float*)d_in[2];
    const int*   rows  = (const int*)d_in[3];
    const int*   cols  = (const int*)d_in[4];
    const float* vals  = (const float*)d_in[5];
    const float* gamma = (const float*)d_in[6];
    const float* beta  = (const float*)d_in[7];
    const int*   idxes_seq = (const int*)d_in[8];   // [2,2] flat
    const int*   idxes_res = (const int*)d_in[9];   // [1,2] flat
    float* out = (float*)d_out;

    // workspace layout: ~80 MB total
    int2*  bins    = (int2*)d_ws;                                // 4E int2 = 51.2 MB
    u16*   s0      = (u16*)(bins + (size_t)N_ADJ * E_EDGES);     // 12.8 MB bf16
    u16*   s1      = s0 + (size_t)N_NODES * DIM;                 // 12.8 MB bf16
    int2*  rowinfo = (int2*)(s1 + (size_t)N_NODES * DIM);        // 3.2 MB
    int*   gcnt    = (int*)(rowinfo + (size_t)N_ADJ * N_NODES);  // 6252 ints
    int*   bbase   = gcnt + NBTOT;                               // 6253 ints
    int*   cursor  = bbase + NBTOT + 1;                          // 6252 ints
    int*   used    = cursor + NBTOT;                             // 4 ints

    hipMemsetAsync(gcnt, 0, (size_t)NBTOT * sizeof(int), stream);

    mask_kernel<<<1, 64, 0, stream>>>(idxes_seq, idxes_res, used);
    gemm_kernel<<<N_NODES / 16, 256, 0, stream>>>(x, W, b, s0);

    dim3 egrid(P1_GRIDX, N_ADJ);
    hist_kernel <<<egrid, P1_BLK, 0, stream>>>(rows, gcnt, used);
    scan_kernel <<<1, P1_BLK, 0, stream>>>(gcnt, bbase, cursor);
    place_kernel<<<egrid, P1_BLK, 0, stream>>>(rows, cols, vals, cursor, bins, used);
    sort_kernel <<<NBTOT, 256, 0, stream>>>(bins, bbase, rowinfo, used);

    // s1 = 0.5*(A[i0]+A[i1]) @ s0
    gather_op_kernel<<<N_NODES / 4, 256, 0, stream>>>(s0, s1, bins, rowinfo, idxes_seq);
    // out = gelu(LN(0.5*(A[i2]+A[i3])@s1 + 0.5*(A[r0]+A[r1])@s0))
    fused_op_ln_gelu_kernel<<<N_NODES / 4, 256, 0, stream>>>(
        s1, s0, out, bins, rowinfo, idxes_seq + 2, idxes_res, gamma, beta);
}

// Round 8
// 501.042 us; speedup vs baseline: 9.6236x; 1.0180x over previous
//
#include <hip/hip_runtime.h>
#include <hip/hip_bf16.h>
#include <math.h>

#define N_NODES 100000
#define DIM 64
#define E_EDGES 1600000
#define N_ADJ 4
#define NB 1563              // ceil(100000/64) buckets of 64 rows
#define NBTOT (N_ADJ * NB)   // 6252
#define P1_BLK 1024
#define P1_CHUNK 12800
#define P1_GRIDX 125         // 125 * 12800 = 1.6M
#define SORT_STAGE 4096      // per-bucket LDS stage; mean load 1024

typedef unsigned short u16;
typedef unsigned int u32;

// ---- used-adjacency mask from device-side idxes ----
__global__ void mask_kernel(const int* __restrict__ iseq,
                            const int* __restrict__ ires,
                            int* __restrict__ used) {
    if (threadIdx.x == 0) {
        used[0] = used[1] = used[2] = used[3] = 0;
        used[iseq[0]] = 1; used[iseq[1]] = 1;
        used[iseq[2]] = 1; used[iseq[3]] = 1;
        used[ires[0]] = 1; used[ires[1]] = 1;
    }
}

// ---------------- GEMM: s0 = bf16(x @ W + b) ----------------
__global__ __launch_bounds__(256) void gemm_kernel(
    const float* __restrict__ x, const float* __restrict__ W,
    const float* __restrict__ b, u16* __restrict__ h) {
    __shared__ float Ws[DIM * DIM];
    __shared__ float xs[16 * DIM];
    const int tid = threadIdx.x;
    const long row0 = (long)blockIdx.x * 16;
    for (int i = tid; i < DIM * DIM; i += 256) Ws[i] = W[i];
    for (int i = tid; i < 16 * DIM; i += 256) xs[i] = x[row0 * DIM + i];
    __syncthreads();
    const int lane = tid & 63;
    const int grp  = tid >> 6;
    const float bias = b[lane];
    #pragma unroll
    for (int rr = 0; rr < 4; ++rr) {
        const int r = grp * 4 + rr;
        float acc = bias;
        #pragma unroll
        for (int k = 0; k < DIM; ++k)
            acc += xs[r * DIM + k] * Ws[k * DIM + lane];
        __hip_bfloat16 hb = __float2bfloat16(acc);
        h[(row0 + r) * DIM + lane] = *(u16*)&hb;
    }
}

// ---- hist: LDS-aggregated bucket counts -> gcnt ----
__global__ __launch_bounds__(1024) void hist_kernel(
    const int* __restrict__ rows, int* __restrict__ gcnt,
    const int* __restrict__ used) {
    __shared__ int h[NB];
    const int a = blockIdx.y;
    if (!used[a]) return;
    const int tid = threadIdx.x;
    const long e0 = (long)a * E_EDGES + (long)blockIdx.x * P1_CHUNK;
    for (int i = tid; i < NB; i += P1_BLK) h[i] = 0;
    __syncthreads();
    for (int i = tid; i < P1_CHUNK; i += P1_BLK)
        atomicAdd(&h[rows[e0 + i] >> 6], 1);
    __syncthreads();
    for (int bk = tid; bk < NB; bk += P1_BLK) {
        const int c = h[bk];
        if (c) atomicAdd(&gcnt[a * NB + bk], c);
    }
}

// ---- scan: exact exclusive scan of 6252 bucket counts (1 block) ----
__global__ __launch_bounds__(1024) void scan_kernel(
    const int* __restrict__ gcnt, int* __restrict__ bbase,
    int* __restrict__ cursor) {
    __shared__ int wsum[16];
    const int tid = threadIdx.x, lane = tid & 63, wave = tid >> 6;
    int pre[7];
    int tsum = 0;
    #pragma unroll
    for (int k = 0; k < 7; ++k) {
        const int idx = tid * 7 + k;
        const int v = (idx < NBTOT) ? gcnt[idx] : 0;
        pre[k] = tsum;
        tsum += v;
    }
    int incl = tsum;
    #pragma unroll
    for (int o = 1; o < 64; o <<= 1) {
        const int t = __shfl_up(incl, o);
        if (lane >= o) incl += t;
    }
    if (lane == 63) wsum[wave] = incl;
    __syncthreads();
    if (tid == 0) {
        int run = 0;
        #pragma unroll
        for (int w = 0; w < 16; ++w) { const int t = wsum[w]; wsum[w] = run; run += t; }
    }
    __syncthreads();
    const int texcl = incl - tsum + wsum[wave];
    #pragma unroll
    for (int k = 0; k < 7; ++k) {
        const int idx = tid * 7 + k;
        if (idx < NBTOT) {
            const int v = texcl + pre[k];
            bbase[idx]  = v;
            cursor[idx] = v;
        }
    }
    if (tid == 0) bbase[NBTOT] = N_ADJ * E_EDGES;
}

// ---- place: reserve per-(block,bucket) runs, pack edges ----
__global__ __launch_bounds__(1024) void place_kernel(
    const int* __restrict__ rows, const int* __restrict__ cols,
    const float* __restrict__ vals, int* __restrict__ cursor,
    int2* __restrict__ bins, const int* __restrict__ used) {
    __shared__ int h[NB];
    const int a = blockIdx.y;
    if (!used[a]) return;
    const int tid = threadIdx.x;
    const long e0 = (long)a * E_EDGES + (long)blockIdx.x * P1_CHUNK;
    for (int i = tid; i < NB; i += P1_BLK) h[i] = 0;
    __syncthreads();
    for (int i = tid; i < P1_CHUNK; i += P1_BLK)
        atomicAdd(&h[rows[e0 + i] >> 6], 1);
    __syncthreads();
    for (int bk = tid; bk < NB; bk += P1_BLK) {
        const int c = h[bk];
        if (c) h[bk] = atomicAdd(&cursor[a * NB + bk], c);  // abs base of run
    }
    __syncthreads();
    for (int i = tid; i < P1_CHUNK; i += P1_BLK) {
        const int r  = rows[e0 + i];
        const int bk = r >> 6;
        const int slot = atomicAdd(&h[bk], 1);              // absolute bins index
        bins[slot] = make_int2((cols[e0 + i] << 6) | (r & 63),
                               __float_as_int(vals[e0 + i]));
    }
}

// ---- sort: per-bucket counting sort by row&63, emit per-row (start,count) ----
__global__ __launch_bounds__(256) void sort_kernel(
    int2* __restrict__ bins, const int* __restrict__ bbase,
    int2* __restrict__ rowinfo, const int* __restrict__ used) {
    __shared__ int2 stage[SORT_STAGE];
    __shared__ int h[64], off[64], cur[64];
    const int a   = blockIdx.x / NB;
    if (!used[a]) return;
    const int tid = threadIdx.x;
    const int bk  = blockIdx.x % NB;
    const int p0  = bbase[blockIdx.x];
    const int n   = min(bbase[blockIdx.x + 1] - p0, SORT_STAGE);

    if (tid < 64) h[tid] = 0;
    __syncthreads();
    for (int i = tid; i < n; i += 256) {
        const int2 e = bins[p0 + i];
        stage[i] = e;
        atomicAdd(&h[e.x & 63], 1);
    }
    __syncthreads();
    if (tid < 64) {
        const int v = h[tid];
        int incl = v;
        #pragma unroll
        for (int o = 1; o < 64; o <<= 1) {
            const int t = __shfl_up(incl, o);
            if (tid >= o) incl += t;
        }
        off[tid] = incl - v;
        cur[tid] = incl - v;
    }
    __syncthreads();
    for (int i = tid; i < n; i += 256) {
        const int2 e = stage[i];
        const int rank = atomicAdd(&cur[e.x & 63], 1);
        bins[p0 + rank] = e;
    }
    if (tid < 64) {
        const int row = bk * 64 + tid;
        if (row < N_NODES)
            rowinfo[a * N_NODES + row] = make_int2(p0 + off[tid], h[tid]);
    }
}

// ---------------- Pull gather, bf16 src, 16 lanes/edge, 4-deep MLP -------
// Wave = 1 row. grp = lane>>4 walks edges grp, grp+4, ... (balanced);
// each macro-iteration batches 4 edge records + 4 row-gathers in flight.
// Edges past the end are predicated to (c=0, v=0): harmless row-0 load.
__device__ __forceinline__ void gather_pair(
    const u16* __restrict__ src, const int2* __restrict__ bins,
    const int2* __restrict__ rowinfo, const int* __restrict__ idx,
    int row, int grp, int sub, float4& acc) {
    const int sb = sub << 2;   // dim offset of this lane's 4 dims
    #pragma unroll
    for (int s = 0; s < 2; ++s) {
        const int2 info = rowinfo[idx[s] * N_NODES + row];
        const int2* eb = bins + info.x;
        const int n = info.y;
        for (int j = grp; j < n; j += 16) {
            const int2 e0 = eb[j];
            const int2 e1 = (j + 4  < n) ? eb[j + 4]  : make_int2(0, 0);
            const int2 e2 = (j + 8  < n) ? eb[j + 8]  : make_int2(0, 0);
            const int2 e3 = (j + 12 < n) ? eb[j + 12] : make_int2(0, 0);
            const uint2 w0 = *(const uint2*)(src + (((u32)(e0.x >> 6) << 6) | sb));
            const uint2 w1 = *(const uint2*)(src + (((u32)(e1.x >> 6) << 6) | sb));
            const uint2 w2 = *(const uint2*)(src + (((u32)(e2.x >> 6) << 6) | sb));
            const uint2 w3 = *(const uint2*)(src + (((u32)(e3.x >> 6) << 6) | sb));
            const float v0 = __int_as_float(e0.y);
            const float v1 = __int_as_float(e1.y);
            const float v2 = __int_as_float(e2.y);
            const float v3 = __int_as_float(e3.y);
            acc.x = fmaf(v0, __int_as_float(w0.x << 16),         acc.x);
            acc.y = fmaf(v0, __int_as_float(w0.x & 0xffff0000u), acc.y);
            acc.z = fmaf(v0, __int_as_float(w0.y << 16),         acc.z);
            acc.w = fmaf(v0, __int_as_float(w0.y & 0xffff0000u), acc.w);
            acc.x = fmaf(v1, __int_as_float(w1.x << 16),         acc.x);
            acc.y = fmaf(v1, __int_as_float(w1.x & 0xffff0000u), acc.y);
            acc.z = fmaf(v1, __int_as_float(w1.y << 16),         acc.z);
            acc.w = fmaf(v1, __int_as_float(w1.y & 0xffff0000u), acc.w);
            acc.x = fmaf(v2, __int_as_float(w2.x << 16),         acc.x);
            acc.y = fmaf(v2, __int_as_float(w2.x & 0xffff0000u), acc.y);
            acc.z = fmaf(v2, __int_as_float(w2.y << 16),         acc.z);
            acc.w = fmaf(v2, __int_as_float(w2.y & 0xffff0000u), acc.w);
            acc.x = fmaf(v3, __int_as_float(w3.x << 16),         acc.x);
            acc.y = fmaf(v3, __int_as_float(w3.x & 0xffff0000u), acc.y);
            acc.z = fmaf(v3, __int_as_float(w3.y << 16),         acc.z);
            acc.w = fmaf(v3, __int_as_float(w3.y & 0xffff0000u), acc.w);
        }
    }
}

__device__ __forceinline__ float4 reduce_groups(float4 t) {
    t.x += __shfl_xor(t.x, 16); t.y += __shfl_xor(t.y, 16);
    t.z += __shfl_xor(t.z, 16); t.w += __shfl_xor(t.w, 16);
    t.x += __shfl_xor(t.x, 32); t.y += __shfl_xor(t.y, 32);
    t.z += __shfl_xor(t.z, 32); t.w += __shfl_xor(t.w, 32);
    return t;
}

// s1 = bf16(0.5*(A[i0]+A[i1]) @ s0)
__global__ __launch_bounds__(256) void gather_op_kernel(
    const u16* __restrict__ src, u16* __restrict__ dst,
    const int2* __restrict__ bins, const int2* __restrict__ rowinfo,
    const int* __restrict__ idx) {
    const int lane = threadIdx.x & 63;
    const int row  = blockIdx.x * 4 + (threadIdx.x >> 6);
    const int grp  = lane >> 4, sub = lane & 15;
    float4 t = make_float4(0.f, 0.f, 0.f, 0.f);
    gather_pair(src, bins, rowinfo, idx, row, grp, sub, t);
    t = reduce_groups(t);
    if (lane < 16) {
        __hip_bfloat16 b0 = __float2bfloat16(0.5f * t.x);
        __hip_bfloat16 b1 = __float2bfloat16(0.5f * t.y);
        __hip_bfloat16 b2 = __float2bfloat16(0.5f * t.z);
        __hip_bfloat16 b3 = __float2bfloat16(0.5f * t.w);
        const u32 lo = (u32)(*(u16*)&b0) | ((u32)(*(u16*)&b1) << 16);
        const u32 hi = (u32)(*(u16*)&b2) | ((u32)(*(u16*)&b3) << 16);
        *(uint2*)(dst + (long)row * DIM + lane * 4) = make_uint2(lo, hi);
    }
}

// out = gelu(LN(0.5*(seq@s1) + 0.5*(res@s0)))
__global__ __launch_bounds__(256) void fused_op_ln_gelu_kernel(
    const u16* __restrict__ s1, const u16* __restrict__ s0,
    float* __restrict__ out, const int2* __restrict__ bins,
    const int2* __restrict__ rowinfo, const int* __restrict__ idx_seq1,
    const int* __restrict__ idx_res, const float* __restrict__ gamma,
    const float* __restrict__ beta) {
    const int lane = threadIdx.x & 63;
    const int row  = blockIdx.x * 4 + (threadIdx.x >> 6);
    const int grp  = lane >> 4, sub = lane & 15;
    float4 t = make_float4(0.f, 0.f, 0.f, 0.f);
    gather_pair(s1, bins, rowinfo, idx_seq1, row, grp, sub, t);
    gather_pair(s0, bins, rowinfo, idx_res,  row, grp, sub, t);
    t.x *= 0.5f; t.y *= 0.5f; t.z *= 0.5f; t.w *= 0.5f;
    t = reduce_groups(t);
    float s  = t.x + t.y + t.z + t.w;
    float s2 = t.x * t.x + t.y * t.y + t.z * t.z + t.w * t.w;
    #pragma unroll
    for (int off = 8; off > 0; off >>= 1) {
        s  += __shfl_xor(s, off);
        s2 += __shfl_xor(s2, off);
    }
    const float mu  = s * (1.0f / DIM);
    const float var = s2 * (1.0f / DIM) - mu * mu;
    const float inv = rsqrtf(var + 1e-5f);
    if (lane < 16) {
        const float4 gm = ((const float4*)gamma)[lane];
        const float4 bt = ((const float4*)beta)[lane];
        float4 y;
        y.x = (t.x - mu) * inv * gm.x + bt.x;
        y.y = (t.y - mu) * inv * gm.y + bt.y;
        y.z = (t.z - mu) * inv * gm.z + bt.z;
        y.w = (t.w - mu) * inv * gm.w + bt.w;
        float4 g;
        g.x = 0.5f * y.x * (1.0f + erff(y.x * 0.70710678118654752f));
        g.y = 0.5f * y.y * (1.0f + erff(y.y * 0.70710678118654752f));
        g.z = 0.5f * y.z * (1.0f + erff(y.z * 0.70710678118654752f));
        g.w = 0.5f * y.w * (1.0f + erff(y.w * 0.70710678118654752f));
        ((float4*)(out + (long)row * DIM))[lane] = g;
    }
}

extern "C" void kernel_launch(void* const* d_in, const int* in_sizes, int n_in,
                              void* d_out, int out_size, void* d_ws, size_t ws_size,
                              hipStream_t stream) {
    const float* x     = (const float*)d_in[0];
    const float* W     = (const float*)d_in[1];
    const float* b     = (const float*)d_in[2];
    const int*   rows  = (const int*)d_in[3];
    const int*   cols  = (const int*)d_in[4];
    const float* vals  = (const float*)d_in[5];
    const float* gamma = (const float*)d_in[6];
    const float* beta  = (const float*)d_in[7];
    const int*   idxes_seq = (const int*)d_in[8];   // [2,2] flat
    const int*   idxes_res = (const int*)d_in[9];   // [1,2] flat
    float* out = (float*)d_out;

    // workspace layout: ~80 MB total
    int2*  bins    = (int2*)d_ws;                                // 4E int2 = 51.2 MB
    u16*   s0      = (u16*)(bins + (size_t)N_ADJ * E_EDGES);     // 12.8 MB bf16
    u16*   s1      = s0 + (size_t)N_NODES * DIM;                 // 12.8 MB bf16
    int2*  rowinfo = (int2*)(s1 + (size_t)N_NODES * DIM);        // 3.2 MB
    int*   gcnt    = (int*)(rowinfo + (size_t)N_ADJ * N_NODES);  // 6252 ints
    int*   bbase   = gcnt + NBTOT;                               // 6253 ints
    int*   cursor  = bbase + NBTOT + 1;                          // 6252 ints
    int*   used    = cursor + NBTOT;                             // 4 ints

    hipMemsetAsync(gcnt, 0, (size_t)NBTOT * sizeof(int), stream);

    mask_kernel<<<1, 64, 0, stream>>>(idxes_seq, idxes_res, used);
    gemm_kernel<<<N_NODES / 16, 256, 0, stream>>>(x, W, b, s0);

    dim3 egrid(P1_GRIDX, N_ADJ);
    hist_kernel <<<egrid, P1_BLK, 0, stream>>>(rows, gcnt, used);
    scan_kernel <<<1, P1_BLK, 0, stream>>>(gcnt, bbase, cursor);
    place_kernel<<<egrid, P1_BLK, 0, stream>>>(rows, cols, vals, cursor, bins, used);
    sort_kernel <<<NBTOT, 256, 0, stream>>>(bins, bbase, rowinfo, used);

    // s1 = 0.5*(A[i0]+A[i1]) @ s0
    gather_op_kernel<<<N_NODES / 4, 256, 0, stream>>>(s0, s1, bins, rowinfo, idxes_seq);
    // out = gelu(LN(0.5*(A[i2]+A[i3])@s1 + 0.5*(A[r0]+A[r1])@s0))
    fused_op_ln_gelu_kernel<<<N_NODES / 4, 256, 0, stream>>>(
        s1, s0, out, bins, rowinfo, idxes_seq + 2, idxes_res, gamma, beta);
}